// Round 12
// baseline (371.434 us; speedup 1.0000x reference)
//
#include <hip/hip_runtime.h>
#include <math.h>
#include <stdint.h>

#define S_    2048
#define SCALE_ 0.044194173824159216f   // 1/sqrt(512)

typedef __attribute__((ext_vector_type(8))) short short8;
typedef __attribute__((ext_vector_type(4))) float f32x4;
typedef __attribute__((ext_vector_type(16))) float f32x16;

#define MFMA16(a, b, c) __builtin_amdgcn_mfma_f32_16x16x32_bf16((a), (b), (c), 0, 0, 0)
#define MFMA32(a, b, c) __builtin_amdgcn_mfma_f32_32x32x16_bf16((a), (b), (c), 0, 0, 0)

__device__ __forceinline__ void glds16(const void* g, void* l) {
  __builtin_amdgcn_global_load_lds(
      (const __attribute__((address_space(1))) void*)g,
      (__attribute__((address_space(3))) void*)l, 16, 0, 0);
}

__device__ __forceinline__ unsigned short f2bf(float f) {
  unsigned u = __float_as_uint(f);
  u += 0x7FFFu + ((u >> 16) & 1u);
  return (unsigned short)(u >> 16);
}

// ---------------------------------------------------------------------------
// fused fp32->bf16 convert for all three inputs (one launch)
__global__ __launch_bounds__(256) void convert3_kernel(
    const float* __restrict__ a, const float* __restrict__ b,
    const float* __restrict__ c, unsigned short* __restrict__ oa,
    unsigned short* __restrict__ ob, unsigned short* __restrict__ oc) {
  int i = blockIdx.x * 256 + threadIdx.x;  // grid covers 3*3145728 float4
  int which = i / 3145728;
  int off = i - which * 3145728;
  const float* s = (which == 0) ? a : (which == 1) ? b : c;
  unsigned short* d = (which == 0) ? oa : (which == 1) ? ob : oc;
  float4 v = ((const float4*)s)[off];
  ushort4 o;
  o.x = f2bf(v.x); o.y = f2bf(v.y); o.z = f2bf(v.z); o.w = f2bf(v.w);
  ((ushort4*)d)[off] = o;
}

// fused init: biases + lsum zero + coh zero (one launch, 64 blocks)
__global__ void init_fused_kernel(const float* __restrict__ bqr,
                                  const float* __restrict__ bqi,
                                  const float* __restrict__ bkr,
                                  const float* __restrict__ bki,
                                  const float* __restrict__ bv, float* bq,
                                  float* bk, float* bvo, float* lsum,
                                  float* coh) {
  int t = blockIdx.x * 256 + threadIdx.x;
  if (t < 512) { bq[t] = bqr[t]; bk[t] = bkr[t]; bvo[t] = bv[t]; }
  else if (t < 1024) { bq[t] = bqi[t - 512]; bk[t] = bki[t - 512]; }
  if (t < 16384) lsum[t] = 0.f;
  if (t == 0) *coh = 0.f;
}

// all 5 weight transposes in one launch: W [768][512] fp32 -> Wt[n][768] bf16
__global__ __launch_bounds__(256) void wtrans_all_kernel(
    const float* __restrict__ Wqr, const float* __restrict__ Wqi,
    const float* __restrict__ Wkr, const float* __restrict__ Wki,
    const float* __restrict__ Wv, unsigned short* __restrict__ WTQ,
    unsigned short* __restrict__ WTK, unsigned short* __restrict__ WTV) {
  __shared__ float t[32][33];
  const float* W;
  unsigned short* Wt;
  int row_off;
  switch (blockIdx.z) {
    case 0: W = Wqr; Wt = WTQ; row_off = 0; break;
    case 1: W = Wqi; Wt = WTQ; row_off = 512; break;
    case 2: W = Wkr; Wt = WTK; row_off = 0; break;
    case 3: W = Wki; Wt = WTK; row_off = 512; break;
    default: W = Wv; Wt = WTV; row_off = 0; break;
  }
  int n0 = blockIdx.x * 32, k0 = blockIdx.y * 32;
  int tx = threadIdx.x & 31, ty = threadIdx.x >> 5;
#pragma unroll
  for (int r = 0; r < 4; ++r)
    t[ty + r * 8][tx] = W[(size_t)(k0 + ty + r * 8) * 512 + n0 + tx];
  __syncthreads();
#pragma unroll
  for (int r = 0; r < 4; ++r)
    Wt[(size_t)(row_off + n0 + ty + r * 8) * 768 + k0 + tx] =
        f2bf(t[tx][ty + r * 8]);
}

// ---------------------------------------------------------------------------
// Fused projection GEMMs (Q, K, V in one launch), round-7 dbuf inner loop.
// ---------------------------------------------------------------------------
__global__ __launch_bounds__(256, 2) void proj_fused_kernel(
    const unsigned short* __restrict__ XQ, const unsigned short* __restrict__ XK,
    const unsigned short* __restrict__ XV, const unsigned short* __restrict__ WTQ,
    const unsigned short* __restrict__ WTK, const unsigned short* __restrict__ WTV,
    const float* __restrict__ BQ, const float* __restrict__ BK,
    const float* __restrict__ BV, unsigned short* __restrict__ QCAT,
    unsigned short* __restrict__ KCAT, unsigned short* __restrict__ VT) {
  __shared__ char lds[65536];   // 2 x (A 16K | B 16K)
  const int tid = threadIdx.x;
  const int lane = tid & 63, wid = tid >> 6;
  const int wi = wid >> 1, wj = wid & 1;

  const unsigned short* Xb;
  const unsigned short* Wt;
  const float* bias;
  unsigned short* Y;
  int N, vt_mode, bx = blockIdx.x;
  if (bx < 8)       { Xb = XQ; Wt = WTQ; bias = BQ; Y = QCAT; N = 1024; vt_mode = 0; }
  else if (bx < 16) { Xb = XK; Wt = WTK; bias = BK; Y = KCAT; N = 1024; vt_mode = 0; bx -= 8; }
  else              { Xb = XV; Wt = WTV; bias = BV; Y = VT;   N = 512;  vt_mode = 1; bx -= 16; }

  const int m0 = blockIdx.y * 128, n0 = bx * 128;
  const char* Xc = (const char*)Xb;
  const char* Wc = (const char*)Wt;
  const int tile = wid >> 1;

  const char* sp[8];
  int sd[8];
#pragma unroll
  for (int iss = 0; iss < 8; ++iss) {
    int gbase = wid * 512 + iss * 64;
    int loc = (gbase & 1023) + lane;
    int r = loc >> 3, blk = loc & 7;
    int sb = blk ^ (r & 7);
    sp[iss] = (tile == 0) ? Xc + (size_t)(m0 + r) * 1536 + sb * 16
                          : Wc + (size_t)(n0 + r) * 1536 + sb * 16;
    sd[iss] = gbase * 16;
  }

  f32x4 acc[4][4] = {};

#pragma unroll
  for (int iss = 0; iss < 8; ++iss) glds16(sp[iss], lds + sd[iss]);

  for (int s = 0; s < 12; ++s) {
    __syncthreads();
    if (s + 1 < 12) {
      char* wb = lds + ((s + 1) & 1) * 32768;
#pragma unroll
      for (int iss = 0; iss < 8; ++iss)
        glds16(sp[iss] + (s + 1) * 128, wb + sd[iss]);
    }
    const char* rb = lds + (s & 1) * 32768;
#pragma unroll
    for (int kk = 0; kk < 2; ++kk) {
      int blk = kk * 4 + (lane >> 4);
      short8 a[4];
#pragma unroll
      for (int i = 0; i < 4; ++i) {
        int row = wi * 64 + i * 16 + (lane & 15);
        a[i] = *(const short8*)(rb + row * 128 + ((blk ^ (row & 7)) << 4));
      }
#pragma unroll
      for (int j = 0; j < 4; ++j) {
        int row = wj * 64 + j * 16 + (lane & 15);
        short8 b = *(const short8*)(rb + 16384 + row * 128 +
                                    ((blk ^ (row & 7)) << 4));
#pragma unroll
        for (int i = 0; i < 4; ++i) acc[i][j] = MFMA16(a[i], b, acc[i][j]);
      }
    }
  }

#pragma unroll
  for (int j = 0; j < 4; ++j) {
    int n = n0 + wj * 64 + j * 16 + (lane & 15);
    float bn = bias[n];
    if (!vt_mode) {
#pragma unroll
      for (int i = 0; i < 4; ++i) {
        int mrow = m0 + wi * 64 + i * 16 + (lane >> 4) * 4;
#pragma unroll
        for (int r = 0; r < 4; ++r)
          Y[(size_t)(mrow + r) * N + n] = f2bf(acc[i][j][r] + bn);
      }
    } else {
#pragma unroll
      for (int i = 0; i < 4; ++i) {
        int mrow = m0 + wi * 64 + i * 16 + (lane >> 4) * 4;
        int b = mrow >> 11, key = mrow & 2047;
        ushort4 o;
        o.x = f2bf(acc[i][j][0] + bn);
        o.y = f2bf(acc[i][j][1] + bn);
        o.z = f2bf(acc[i][j][2] + bn);
        o.w = f2bf(acc[i][j][3] + bn);
        *(ushort4*)&Y[((size_t)b * 512 + n) * 2048 + key] = o;
      }
    }
  }
}

// ---------------------------------------------------------------------------
// Score kernel: round-9 geometry (128x128 tile, 4 waves 2Mx2N 64x64/wave,
// BK=64 dual-half, dbuf 2x32KB, prefetch-after-barrier, 2 blocks/CU) but
// with 32x32x16 MFMA: half the instructions, +15% rate, same data volume.
// A/B: lane = (row/col = lane&31, k-octet = lane>>5), 8 contiguous bf16.
// C/D: col=lane&31, row=(reg&3)+8*(reg>>2)+4*(lane>>5)  [m74/m101].
// ---------------------------------------------------------------------------
__global__ __launch_bounds__(256, 2) void score_kernel(
    const unsigned short* __restrict__ Qcat,
    const unsigned short* __restrict__ Kcat, unsigned short* __restrict__ P,
    float* __restrict__ lsum, float* __restrict__ coh) {
  __shared__ char lds[65536];   // 2 x (Q 16K | K 16K)
  const int tid = threadIdx.x;
  const int lane = tid & 63, wid = tid >> 6;
  const int wm = wid >> 1;   // 0..1 : 64-row M half
  const int wn = wid & 1;    // 0..1 : 64-col N half
  const int g = lane >> 5;   // k-octet group (0..1)
  const int c31 = lane & 31; // A-row / B-col / C-col within 32-block
  const int l8 = lane >> 3, lb = lane & 7;

  const int id = blockIdx.x;
  const int w = (id & 7) * 256 + (id >> 3);   // batch pinned per XCD
  const int batch = w >> 8;
  const int tilein = w & 255;
  const int q0 = (tilein >> 4) << 7;
  const int k0 = (tilein & 15) << 7;

  const char* Qc = (const char*)Qcat + ((size_t)batch * 2048 + q0) * 2048;
  const char* Kc = (const char*)Kcat + ((size_t)batch * 2048 + k0) * 2048;

  // staging identical to round-9: 32 chunks of 1KB, 8 per wave.
  const char* sp[8];
  int sd[8];
#pragma unroll
  for (int u = 0; u < 8; ++u) {
    int L = wid * 8 + u;
    int row = ((L & 15) << 3) + l8;
    int sb = lb ^ (row & 7);
    const char* base = (L < 16) ? Qc : Kc;
    sp[u] = base + (size_t)row * 2048 + (sb & 3) * 16 + (sb >> 2) * 1024;
    sd[u] = L << 10;
  }

  // fragment offsets: per (row-block, K16-slice); lo blocks 0..3, hi 4..7
  int aoff_lo[2][2], aoff_hi[2][2], boff_lo[2][2], boff_hi[2][2];
#pragma unroll
  for (int ar = 0; ar < 2; ++ar) {
    int row = wm * 64 + ar * 32 + c31;
#pragma unroll
    for (int sl = 0; sl < 2; ++sl) {
      aoff_lo[ar][sl] = row * 128 + (((2 * sl + g) ^ (row & 7)) << 4);
      aoff_hi[ar][sl] = row * 128 + (((4 + 2 * sl + g) ^ (row & 7)) << 4);
    }
  }
#pragma unroll
  for (int bc = 0; bc < 2; ++bc) {
    int row = wn * 64 + bc * 32 + c31;
#pragma unroll
    for (int sl = 0; sl < 2; ++sl) {
      boff_lo[bc][sl] = 16384 + row * 128 + (((2 * sl + g) ^ (row & 7)) << 4);
      boff_hi[bc][sl] = 16384 + row * 128 + (((4 + 2 * sl + g) ^ (row & 7)) << 4);
    }
  }

  f32x16 accre[2][2] = {}, accim[2][2] = {};
  const short sg = (short)0x8000;
  const short8 SGN = {sg, sg, sg, sg, sg, sg, sg, sg};

#pragma unroll
  for (int u = 0; u < 8; ++u) glds16(sp[u], lds + sd[u]);

  for (int t = 0; t < 16; ++t) {
    __syncthreads();   // buf[t&1] ready (prefetch had a full step to land)
    if (t + 1 < 16) {
      char* wb = lds + ((t + 1) & 1) * 32768;
#pragma unroll
      for (int u = 0; u < 8; ++u) glds16(sp[u] + (t + 1) * 64, wb + sd[u]);
    }
    const char* rb = lds + (t & 1) * 32768;
#pragma unroll
    for (int sl = 0; sl < 2; ++sl) {
      short8 alo[2], ahi[2];
#pragma unroll
      for (int ar = 0; ar < 2; ++ar) {
        alo[ar] = *(const short8*)(rb + aoff_lo[ar][sl]);
        ahi[ar] = *(const short8*)(rb + aoff_hi[ar][sl]);
      }
#pragma unroll
      for (int bc = 0; bc < 2; ++bc) {
        short8 blo = *(const short8*)(rb + boff_lo[bc][sl]);
        short8 bhi = *(const short8*)(rb + boff_hi[bc][sl]);
        short8 bhin = bhi ^ SGN;
#pragma unroll
        for (int ar = 0; ar < 2; ++ar) {
          accre[ar][bc] = MFMA32(alo[ar], blo, accre[ar][bc]);
          accre[ar][bc] = MFMA32(ahi[ar], bhi, accre[ar][bc]);
          accim[ar][bc] = MFMA32(ahi[ar], blo, accim[ar][bc]);
          accim[ar][bc] = MFMA32(alo[ar], bhin, accim[ar][bc]);
        }
      }
    }
  }

  // epilogue: coherence, p=exp(mag*scale), P store, row sums
  float csum = 0.f;
  size_t prow_base = (size_t)batch * 2048;
#pragma unroll
  for (int ar = 0; ar < 2; ++ar) {
#pragma unroll
    for (int r = 0; r < 16; ++r) {
      int row = q0 + wm * 64 + ar * 32 + (r & 3) + 8 * (r >> 2) + 4 * g;
      unsigned short* prow = P + (prow_base + row) * 2048;
      float rs = 0.f;
#pragma unroll
      for (int bc = 0; bc < 2; ++bc) {
        float re = accre[ar][bc][r], im = accim[ar][bc][r];
        csum += im * im;
        float p = __expf(sqrtf(re * re + im * im) * SCALE_);
        rs += p;
        prow[k0 + wn * 64 + bc * 32 + c31] = f2bf(p);
      }
      rs += __shfl_xor(rs, 1, 64);
      rs += __shfl_xor(rs, 2, 64);
      rs += __shfl_xor(rs, 4, 64);
      rs += __shfl_xor(rs, 8, 64);
      rs += __shfl_xor(rs, 16, 64);
      if (c31 == 0) atomicAdd(&lsum[prow_base + row], rs);
    }
  }
#pragma unroll
  for (int m = 1; m < 64; m <<= 1) csum += __shfl_xor(csum, m, 64);
  float* cred = (float*)lds;
  __syncthreads();             // all compute reads done before reusing lds
  if (lane == 0) cred[wid] = csum;
  __syncthreads();
  if (tid == 0) atomicAdd(coh, cred[0] + cred[1] + cred[2] + cred[3]);
}

// ---------------------------------------------------------------------------
// PV GEMM, double-buffered (round-7 form): out = (P @ Vt^T) / lsum
// ---------------------------------------------------------------------------
__global__ __launch_bounds__(256, 2) void pv_kernel(
    const unsigned short* __restrict__ P, const unsigned short* __restrict__ Vt,
    const float* __restrict__ lsum, float* __restrict__ out) {
  __shared__ char lds[65536];   // 2 x (P 16K | V 16K)
  const int tid = threadIdx.x;
  const int lane = tid & 63, wid = tid >> 6;
  const int wi = wid >> 1, wj = wid & 1;

  int id = blockIdx.x;
  int w = (id & 7) * 64 + (id >> 3);
  int batch = w >> 6, tilein = w & 63;
  int i0 = (tilein >> 2) * 128;
  int o0 = (tilein & 3) * 128;

  const char* Pc = (const char*)P + (size_t)batch * 2048 * 4096;
  const char* Vc = (const char*)Vt + (size_t)batch * 512 * 4096;
  const int tile = wid >> 1;

  const char* sp[8];
  int sd[8];
#pragma unroll
  for (int iss = 0; iss < 8; ++iss) {
    int gbase = wid * 512 + iss * 64;
    int loc = (gbase & 1023) + lane;
    int r = loc >> 3, blk = loc & 7;
    int sb = blk ^ (r & 7);
    sp[iss] = (tile == 0) ? Pc + (size_t)(i0 + r) * 4096 + sb * 16
                          : Vc + (size_t)(o0 + r) * 4096 + sb * 16;
    sd[iss] = gbase * 16;
  }

  f32x4 acc[4][4] = {};

#pragma unroll
  for (int iss = 0; iss < 8; ++iss) glds16(sp[iss], lds + sd[iss]);

  for (int s = 0; s < 32; ++s) {
    __syncthreads();
    if (s + 1 < 32) {
      char* wb = lds + ((s + 1) & 1) * 32768;
#pragma unroll
      for (int iss = 0; iss < 8; ++iss)
        glds16(sp[iss] + (s + 1) * 128, wb + sd[iss]);
    }
    const char* rb = lds + (s & 1) * 32768;
#pragma unroll
    for (int kk = 0; kk < 2; ++kk) {
      int blk = kk * 4 + (lane >> 4);
      short8 a[4];
#pragma unroll
      for (int i = 0; i < 4; ++i) {
        int row = wi * 64 + i * 16 + (lane & 15);
        a[i] = *(const short8*)(rb + row * 128 + ((blk ^ (row & 7)) << 4));
      }
#pragma unroll
      for (int j = 0; j < 4; ++j) {
        int row = wj * 64 + j * 16 + (lane & 15);
        short8 b = *(const short8*)(rb + 16384 + row * 128 +
                                    ((blk ^ (row & 7)) << 4));
#pragma unroll
        for (int i = 0; i < 4; ++i) acc[i][j] = MFMA16(a[i], b, acc[i][j]);
      }
    }
  }

#pragma unroll
  for (int i = 0; i < 4; ++i) {
    int mrow = i0 + wi * 64 + i * 16 + (lane >> 4) * 4;
    float linv[4];
#pragma unroll
    for (int r = 0; r < 4; ++r)
      linv[r] = 1.0f / lsum[(size_t)batch * 2048 + mrow + r];
#pragma unroll
    for (int j = 0; j < 4; ++j) {
      int n = o0 + wj * 64 + j * 16 + (lane & 15);
#pragma unroll
      for (int r = 0; r < 4; ++r)
        out[((size_t)batch * 2048 + mrow + r) * 512 + n] = acc[i][j][r] * linv[r];
    }
  }
}

__global__ void finalize_kernel(const float* __restrict__ coh,
                                const float* __restrict__ cw,
                                float* __restrict__ out_last) {
  *out_last = (*coh) * (1.0f / 33554432.0f) * (*cw);
}

// ---------------------------------------------------------------------------
extern "C" void kernel_launch(void* const* d_in, const int* in_sizes, int n_in,
                              void* d_out, int out_size, void* d_ws,
                              size_t ws_size, hipStream_t stream) {
  const float* query = (const float*)d_in[0];
  const float* key   = (const float*)d_in[1];
  const float* value = (const float*)d_in[2];
  const float* Wqr = (const float*)d_in[3];
  const float* bqr = (const float*)d_in[4];
  const float* Wqi = (const float*)d_in[5];
  const float* bqi = (const float*)d_in[6];
  const float* Wkr = (const float*)d_in[7];
  const float* bkr = (const float*)d_in[8];
  const float* Wki = (const float*)d_in[9];
  const float* bki = (const float*)d_in[10];
  const float* Wv  = (const float*)d_in[11];
  const float* bv  = (const float*)d_in[12];
  const float* cw  = (const float*)d_in[13];
  float* out = (float*)d_out;

  char* ws = (char*)d_ws;
  unsigned short* XQ   = (unsigned short*)(ws + 0);
  unsigned short* XK   = (unsigned short*)(ws + 25165824);
  unsigned short* XV   = (unsigned short*)(ws + 50331648);
  unsigned short* Pbuf = (unsigned short*)(ws + 0);          // overlays X after proj
  unsigned short* WTQ  = (unsigned short*)(ws + 75497472);
  unsigned short* WTK  = (unsigned short*)(ws + 77070336);
  unsigned short* WTV  = (unsigned short*)(ws + 78643200);
  float* BQ   = (float*)(ws + 79429632);
  float* BK   = (float*)(ws + 79433728);
  float* BV   = (float*)(ws + 79437824);
  unsigned short* QCAT = (unsigned short*)(ws + 79441920);
  unsigned short* KCAT = (unsigned short*)(ws + 112996352);
  unsigned short* VT   = (unsigned short*)(ws + 146550784);
  float* LSUM = (float*)(ws + 163328000);
  float* COH  = (float*)(ws + 163393536);
  if (ws_size < 163393600) return;

  convert3_kernel<<<36864, 256, 0, stream>>>(query, key, value, XQ, XK, XV);
  init_fused_kernel<<<64, 256, 0, stream>>>(bqr, bqi, bkr, bki, bv, BQ, BK, BV,
                                            LSUM, COH);
  wtrans_all_kernel<<<dim3(16, 24, 5), 256, 0, stream>>>(Wqr, Wqi, Wkr, Wki, Wv,
                                                         WTQ, WTK, WTV);

  proj_fused_kernel<<<dim3(20, 128), 256, 0, stream>>>(
      XQ, XK, XV, WTQ, WTK, WTV, BQ, BK, BV, QCAT, KCAT, VT);

  score_kernel<<<2048, 256, 0, stream>>>(QCAT, KCAT, Pbuf, LSUM, COH);
  pv_kernel<<<512, 256, 0, stream>>>(Pbuf, VT, LSUM, out);
  finalize_kernel<<<1, 1, 0, stream>>>(COH, cw, out + 8388608);
}

// Round 13
// 331.143 us; speedup vs baseline: 1.1217x; 1.1217x over previous
//
#include <hip/hip_runtime.h>
#include <math.h>
#include <stdint.h>

#define S_    2048
#define SCALE_ 0.044194173824159216f   // 1/sqrt(512)

typedef __attribute__((ext_vector_type(8))) short short8;
typedef __attribute__((ext_vector_type(4))) float f32x4;

#define MFMA16(a, b, c) __builtin_amdgcn_mfma_f32_16x16x32_bf16((a), (b), (c), 0, 0, 0)

__device__ __forceinline__ void glds16(const void* g, void* l) {
  __builtin_amdgcn_global_load_lds(
      (const __attribute__((address_space(1))) void*)g,
      (__attribute__((address_space(3))) void*)l, 16, 0, 0);
}

__device__ __forceinline__ unsigned short f2bf(float f) {
  unsigned u = __float_as_uint(f);
  u += 0x7FFFu + ((u >> 16) & 1u);
  return (unsigned short)(u >> 16);
}

// ---------------------------------------------------------------------------
// Merged prologue: fp32->bf16 convert (blocks 0..36863), 5 weight transposes
// (blocks 36864..38783), bias/lsum/coh init (blocks 38784..38847).
// All portions fully independent -> safe in one launch.
// ---------------------------------------------------------------------------
__global__ __launch_bounds__(256) void prologue_kernel(
    const float* __restrict__ q, const float* __restrict__ k,
    const float* __restrict__ v, unsigned short* __restrict__ XQ,
    unsigned short* __restrict__ XK, unsigned short* __restrict__ XV,
    const float* __restrict__ Wqr, const float* __restrict__ Wqi,
    const float* __restrict__ Wkr, const float* __restrict__ Wki,
    const float* __restrict__ Wv, unsigned short* __restrict__ WTQ,
    unsigned short* __restrict__ WTK, unsigned short* __restrict__ WTV,
    const float* __restrict__ bqr, const float* __restrict__ bqi,
    const float* __restrict__ bkr, const float* __restrict__ bki,
    const float* __restrict__ bv, float* __restrict__ BQ,
    float* __restrict__ BK, float* __restrict__ BV, float* __restrict__ lsum,
    float* __restrict__ coh) {
  __shared__ float t[32][33];
  const int id = blockIdx.x;
  if (id < 36864) {
    // ---- convert: 3 * 3145728 float4 ----
    int i = id * 256 + threadIdx.x;
    int which = i / 3145728;
    int off = i - which * 3145728;
    const float* s = (which == 0) ? q : (which == 1) ? k : v;
    unsigned short* d = (which == 0) ? XQ : (which == 1) ? XK : XV;
    float4 vv = ((const float4*)s)[off];
    ushort4 o;
    o.x = f2bf(vv.x); o.y = f2bf(vv.y); o.z = f2bf(vv.z); o.w = f2bf(vv.w);
    ((ushort4*)d)[off] = o;
  } else if (id < 38784) {
    // ---- wtrans: W [768][512] fp32 -> Wt[row_off + n][768] bf16 ----
    int id2 = id - 36864;
    int z = id2 / 384, rem = id2 - z * 384;
    int n0 = (rem & 15) * 32, k0 = (rem >> 4) * 32;
    const float* W;
    unsigned short* Wt;
    int row_off;
    switch (z) {
      case 0: W = Wqr; Wt = WTQ; row_off = 0; break;
      case 1: W = Wqi; Wt = WTQ; row_off = 512; break;
      case 2: W = Wkr; Wt = WTK; row_off = 0; break;
      case 3: W = Wki; Wt = WTK; row_off = 512; break;
      default: W = Wv; Wt = WTV; row_off = 0; break;
    }
    int tx = threadIdx.x & 31, ty = threadIdx.x >> 5;
#pragma unroll
    for (int r = 0; r < 4; ++r)
      t[ty + r * 8][tx] = W[(size_t)(k0 + ty + r * 8) * 512 + n0 + tx];
    __syncthreads();
#pragma unroll
    for (int r = 0; r < 4; ++r)
      Wt[(size_t)(row_off + n0 + ty + r * 8) * 768 + k0 + tx] =
          f2bf(t[tx][ty + r * 8]);
  } else {
    // ---- init: biases + lsum + coh ----
    int tt = (id - 38784) * 256 + threadIdx.x;
    if (tt < 512) { BQ[tt] = bqr[tt]; BK[tt] = bkr[tt]; BV[tt] = bv[tt]; }
    else if (tt < 1024) { BQ[tt] = bqi[tt - 512]; BK[tt] = bki[tt - 512]; }
    if (tt < 16384) lsum[tt] = 0.f;
    if (tt == 0) *coh = 0.f;
  }
}

// ---------------------------------------------------------------------------
// Fused projection GEMMs (Q, K, V in one launch), dbuf inner loop.
// Y[M,N] = Xb[M,768] @ Wt[N,768]^T + bias. 128x128 block, 4 waves, BK=64.
// grid.x: 0..7 Q-cols, 8..15 K-cols, 16..19 V-cols.
// ---------------------------------------------------------------------------
__global__ __launch_bounds__(256, 2) void proj_fused_kernel(
    const unsigned short* __restrict__ XQ, const unsigned short* __restrict__ XK,
    const unsigned short* __restrict__ XV, const unsigned short* __restrict__ WTQ,
    const unsigned short* __restrict__ WTK, const unsigned short* __restrict__ WTV,
    const float* __restrict__ BQ, const float* __restrict__ BK,
    const float* __restrict__ BV, unsigned short* __restrict__ QCAT,
    unsigned short* __restrict__ KCAT, unsigned short* __restrict__ VT) {
  __shared__ char lds[65536];   // 2 x (A 16K | B 16K)
  const int tid = threadIdx.x;
  const int lane = tid & 63, wid = tid >> 6;
  const int wi = wid >> 1, wj = wid & 1;

  const unsigned short* Xb;
  const unsigned short* Wt;
  const float* bias;
  unsigned short* Y;
  int N, vt_mode, bx = blockIdx.x;
  if (bx < 8)       { Xb = XQ; Wt = WTQ; bias = BQ; Y = QCAT; N = 1024; vt_mode = 0; }
  else if (bx < 16) { Xb = XK; Wt = WTK; bias = BK; Y = KCAT; N = 1024; vt_mode = 0; bx -= 8; }
  else              { Xb = XV; Wt = WTV; bias = BV; Y = VT;   N = 512;  vt_mode = 1; bx -= 16; }

  const int m0 = blockIdx.y * 128, n0 = bx * 128;
  const char* Xc = (const char*)Xb;
  const char* Wc = (const char*)Wt;
  const int tile = wid >> 1;

  const char* sp[8];
  int sd[8];
#pragma unroll
  for (int iss = 0; iss < 8; ++iss) {
    int gbase = wid * 512 + iss * 64;
    int loc = (gbase & 1023) + lane;
    int r = loc >> 3, blk = loc & 7;
    int sb = blk ^ (r & 7);
    sp[iss] = (tile == 0) ? Xc + (size_t)(m0 + r) * 1536 + sb * 16
                          : Wc + (size_t)(n0 + r) * 1536 + sb * 16;
    sd[iss] = gbase * 16;
  }

  f32x4 acc[4][4] = {};

#pragma unroll
  for (int iss = 0; iss < 8; ++iss) glds16(sp[iss], lds + sd[iss]);

  for (int s = 0; s < 12; ++s) {
    __syncthreads();
    if (s + 1 < 12) {
      char* wb = lds + ((s + 1) & 1) * 32768;
#pragma unroll
      for (int iss = 0; iss < 8; ++iss)
        glds16(sp[iss] + (s + 1) * 128, wb + sd[iss]);
    }
    const char* rb = lds + (s & 1) * 32768;
#pragma unroll
    for (int kk = 0; kk < 2; ++kk) {
      int blk = kk * 4 + (lane >> 4);
      short8 a[4];
#pragma unroll
      for (int i = 0; i < 4; ++i) {
        int row = wi * 64 + i * 16 + (lane & 15);
        a[i] = *(const short8*)(rb + row * 128 + ((blk ^ (row & 7)) << 4));
      }
#pragma unroll
      for (int j = 0; j < 4; ++j) {
        int row = wj * 64 + j * 16 + (lane & 15);
        short8 b = *(const short8*)(rb + 16384 + row * 128 +
                                    ((blk ^ (row & 7)) << 4));
#pragma unroll
        for (int i = 0; i < 4; ++i) acc[i][j] = MFMA16(a[i], b, acc[i][j]);
      }
    }
  }

#pragma unroll
  for (int j = 0; j < 4; ++j) {
    int n = n0 + wj * 64 + j * 16 + (lane & 15);
    float bn = bias[n];
    if (!vt_mode) {
#pragma unroll
      for (int i = 0; i < 4; ++i) {
        int mrow = m0 + wi * 64 + i * 16 + (lane >> 4) * 4;
#pragma unroll
        for (int r = 0; r < 4; ++r)
          Y[(size_t)(mrow + r) * N + n] = f2bf(acc[i][j][r] + bn);
      }
    } else {
#pragma unroll
      for (int i = 0; i < 4; ++i) {
        int mrow = m0 + wi * 64 + i * 16 + (lane >> 4) * 4;
        int b = mrow >> 11, key = mrow & 2047;
        ushort4 o;
        o.x = f2bf(acc[i][j][0] + bn);
        o.y = f2bf(acc[i][j][1] + bn);
        o.z = f2bf(acc[i][j][2] + bn);
        o.w = f2bf(acc[i][j][3] + bn);
        *(ushort4*)&Y[((size_t)b * 512 + n) * 2048 + key] = o;
      }
    }
  }
}

// ---------------------------------------------------------------------------
// Score kernel (best-known round-9 form): 128x128 tile, 4 waves (2Mx2N,
// 64x64/wave), BK=64 dual-half rows, dbuf 2x32KB, prefetch-after-barrier,
// 2 blocks/CU, 16x16x32 MFMA (conflict-free under row&7 XOR).
// ---------------------------------------------------------------------------
__global__ __launch_bounds__(256, 2) void score_kernel(
    const unsigned short* __restrict__ Qcat,
    const unsigned short* __restrict__ Kcat, unsigned short* __restrict__ P,
    float* __restrict__ lsum, float* __restrict__ coh) {
  __shared__ char lds[65536];   // 2 x (Q 16K | K 16K)
  const int tid = threadIdx.x;
  const int lane = tid & 63, wid = tid >> 6;
  const int wm = wid >> 1;   // 0..1 : 64-row M half
  const int wn = wid & 1;    // 0..1 : 64-col N half
  const int lr = lane & 15;
  const int lk = lane >> 4;
  const int l8 = lane >> 3, lb = lane & 7;

  const int id = blockIdx.x;
  const int w = (id & 7) * 256 + (id >> 3);   // batch pinned per XCD
  const int batch = w >> 8;
  const int tilein = w & 255;
  const int q0 = (tilein >> 4) << 7;
  const int k0 = (tilein & 15) << 7;

  const char* Qc = (const char*)Qcat + ((size_t)batch * 2048 + q0) * 2048;
  const char* Kc = (const char*)Kcat + ((size_t)batch * 2048 + k0) * 2048;

  const char* sp[8];
  int sd[8];
#pragma unroll
  for (int u = 0; u < 8; ++u) {
    int L = wid * 8 + u;
    int row = ((L & 15) << 3) + l8;
    int sb = lb ^ (row & 7);
    const char* base = (L < 16) ? Qc : Kc;
    sp[u] = base + (size_t)row * 2048 + (sb & 3) * 16 + (sb >> 2) * 1024;
    sd[u] = L << 10;
  }

  int aoff_lo[4], aoff_hi[4], boff_lo[4], boff_hi[4];
#pragma unroll
  for (int i = 0; i < 4; ++i) {
    int ar = wm * 64 + i * 16 + lr;
    aoff_lo[i] = ar * 128 + ((lk ^ (ar & 7)) << 4);
    aoff_hi[i] = ar * 128 + (((4 + lk) ^ (ar & 7)) << 4);
  }
#pragma unroll
  for (int j = 0; j < 4; ++j) {
    int br = wn * 64 + j * 16 + lr;
    boff_lo[j] = 16384 + br * 128 + ((lk ^ (br & 7)) << 4);
    boff_hi[j] = 16384 + br * 128 + (((4 + lk) ^ (br & 7)) << 4);
  }

  f32x4 accre[4][4] = {}, accim[4][4] = {};
  const short sg = (short)0x8000;
  const short8 SGN = {sg, sg, sg, sg, sg, sg, sg, sg};

#pragma unroll
  for (int u = 0; u < 8; ++u) glds16(sp[u], lds + sd[u]);

  for (int t = 0; t < 16; ++t) {
    __syncthreads();
    if (t + 1 < 16) {
      char* wb = lds + ((t + 1) & 1) * 32768;
#pragma unroll
      for (int u = 0; u < 8; ++u) glds16(sp[u] + (t + 1) * 64, wb + sd[u]);
    }
    const char* rb = lds + (t & 1) * 32768;
    short8 alo[4], ahi[4];
#pragma unroll
    for (int i = 0; i < 4; ++i) {
      alo[i] = *(const short8*)(rb + aoff_lo[i]);
      ahi[i] = *(const short8*)(rb + aoff_hi[i]);
    }
#pragma unroll
    for (int j = 0; j < 4; ++j) {
      short8 blo = *(const short8*)(rb + boff_lo[j]);
      short8 bhi = *(const short8*)(rb + boff_hi[j]);
      short8 bhin = bhi ^ SGN;
#pragma unroll
      for (int i = 0; i < 4; ++i) {
        accre[i][j] = MFMA16(alo[i], blo, accre[i][j]);
        accre[i][j] = MFMA16(ahi[i], bhi, accre[i][j]);
        accim[i][j] = MFMA16(ahi[i], blo, accim[i][j]);
        accim[i][j] = MFMA16(alo[i], bhin, accim[i][j]);
      }
    }
  }

  // epilogue: coherence, p=exp(mag*scale), P store, row sums
  float csum = 0.f;
  size_t prow_base = (size_t)batch * 2048;
#pragma unroll
  for (int i = 0; i < 4; ++i) {
#pragma unroll
    for (int r = 0; r < 4; ++r) {
      int row = q0 + wm * 64 + i * 16 + lk * 4 + r;
      unsigned short* prow = P + (prow_base + row) * 2048;
      float rs = 0.f;
#pragma unroll
      for (int j = 0; j < 4; ++j) {
        float re = accre[i][j][r], im = accim[i][j][r];
        csum += im * im;
        float p = __expf(sqrtf(re * re + im * im) * SCALE_);
        rs += p;
        prow[k0 + wn * 64 + j * 16 + lr] = f2bf(p);
      }
      rs += __shfl_xor(rs, 1, 64);
      rs += __shfl_xor(rs, 2, 64);
      rs += __shfl_xor(rs, 4, 64);
      rs += __shfl_xor(rs, 8, 64);
      if (lr == 0) atomicAdd(&lsum[prow_base + row], rs);
    }
  }
#pragma unroll
  for (int m = 1; m < 64; m <<= 1) csum += __shfl_xor(csum, m, 64);
  float* cred = (float*)lds;
  __syncthreads();             // all compute reads done before reusing lds
  if (lane == 0) cred[wid] = csum;
  __syncthreads();
  if (tid == 0) atomicAdd(coh, cred[0] + cred[1] + cred[2] + cred[3]);
}

// ---------------------------------------------------------------------------
// PV GEMM, double-buffered: out = (P @ Vt^T) / lsum
// ---------------------------------------------------------------------------
__global__ __launch_bounds__(256, 2) void pv_kernel(
    const unsigned short* __restrict__ P, const unsigned short* __restrict__ Vt,
    const float* __restrict__ lsum, float* __restrict__ out) {
  __shared__ char lds[65536];   // 2 x (P 16K | V 16K)
  const int tid = threadIdx.x;
  const int lane = tid & 63, wid = tid >> 6;
  const int wi = wid >> 1, wj = wid & 1;

  int id = blockIdx.x;
  int w = (id & 7) * 64 + (id >> 3);
  int batch = w >> 6, tilein = w & 63;
  int i0 = (tilein >> 2) * 128;
  int o0 = (tilein & 3) * 128;

  const char* Pc = (const char*)P + (size_t)batch * 2048 * 4096;
  const char* Vc = (const char*)Vt + (size_t)batch * 512 * 4096;
  const int tile = wid >> 1;

  const char* sp[8];
  int sd[8];
#pragma unroll
  for (int iss = 0; iss < 8; ++iss) {
    int gbase = wid * 512 + iss * 64;
    int loc = (gbase & 1023) + lane;
    int r = loc >> 3, blk = loc & 7;
    int sb = blk ^ (r & 7);
    sp[iss] = (tile == 0) ? Pc + (size_t)(i0 + r) * 4096 + sb * 16
                          : Vc + (size_t)(o0 + r) * 4096 + sb * 16;
    sd[iss] = gbase * 16;
  }

  f32x4 acc[4][4] = {};

#pragma unroll
  for (int iss = 0; iss < 8; ++iss) glds16(sp[iss], lds + sd[iss]);

  for (int s = 0; s < 32; ++s) {
    __syncthreads();
    if (s + 1 < 32) {
      char* wb = lds + ((s + 1) & 1) * 32768;
#pragma unroll
      for (int iss = 0; iss < 8; ++iss)
        glds16(sp[iss] + (s + 1) * 128, wb + sd[iss]);
    }
    const char* rb = lds + (s & 1) * 32768;
#pragma unroll
    for (int kk = 0; kk < 2; ++kk) {
      int blk = kk * 4 + (lane >> 4);
      short8 a[4];
#pragma unroll
      for (int i = 0; i < 4; ++i) {
        int row = wi * 64 + i * 16 + (lane & 15);
        a[i] = *(const short8*)(rb + row * 128 + ((blk ^ (row & 7)) << 4));
      }
#pragma unroll
      for (int j = 0; j < 4; ++j) {
        int row = wj * 64 + j * 16 + (lane & 15);
        short8 b = *(const short8*)(rb + 16384 + row * 128 +
                                    ((blk ^ (row & 7)) << 4));
#pragma unroll
        for (int i = 0; i < 4; ++i) acc[i][j] = MFMA16(a[i], b, acc[i][j]);
      }
    }
  }

#pragma unroll
  for (int i = 0; i < 4; ++i) {
    int mrow = i0 + wi * 64 + i * 16 + (lane >> 4) * 4;
    float linv[4];
#pragma unroll
    for (int r = 0; r < 4; ++r)
      linv[r] = 1.0f / lsum[(size_t)batch * 2048 + mrow + r];
#pragma unroll
    for (int j = 0; j < 4; ++j) {
      int n = o0 + wj * 64 + j * 16 + (lane & 15);
#pragma unroll
      for (int r = 0; r < 4; ++r)
        out[((size_t)batch * 2048 + mrow + r) * 512 + n] = acc[i][j][r] * linv[r];
    }
  }
}

__global__ void finalize_kernel(const float* __restrict__ coh,
                                const float* __restrict__ cw,
                                float* __restrict__ out_last) {
  *out_last = (*coh) * (1.0f / 33554432.0f) * (*cw);
}

// ---------------------------------------------------------------------------
extern "C" void kernel_launch(void* const* d_in, const int* in_sizes, int n_in,
                              void* d_out, int out_size, void* d_ws,
                              size_t ws_size, hipStream_t stream) {
  const float* query = (const float*)d_in[0];
  const float* key   = (const float*)d_in[1];
  const float* value = (const float*)d_in[2];
  const float* Wqr = (const float*)d_in[3];
  const float* bqr = (const float*)d_in[4];
  const float* Wqi = (const float*)d_in[5];
  const float* bqi = (const float*)d_in[6];
  const float* Wkr = (const float*)d_in[7];
  const float* bkr = (const float*)d_in[8];
  const float* Wki = (const float*)d_in[9];
  const float* bki = (const float*)d_in[10];
  const float* Wv  = (const float*)d_in[11];
  const float* bv  = (const float*)d_in[12];
  const float* cw  = (const float*)d_in[13];
  float* out = (float*)d_out;

  char* ws = (char*)d_ws;
  unsigned short* XQ   = (unsigned short*)(ws + 0);
  unsigned short* XK   = (unsigned short*)(ws + 25165824);
  unsigned short* XV   = (unsigned short*)(ws + 50331648);
  unsigned short* Pbuf = (unsigned short*)(ws + 0);          // overlays X after proj
  unsigned short* WTQ  = (unsigned short*)(ws + 75497472);
  unsigned short* WTK  = (unsigned short*)(ws + 77070336);
  unsigned short* WTV  = (unsigned short*)(ws + 78643200);
  float* BQ   = (float*)(ws + 79429632);
  float* BK   = (float*)(ws + 79433728);
  float* BV   = (float*)(ws + 79437824);
  unsigned short* QCAT = (unsigned short*)(ws + 79441920);
  unsigned short* KCAT = (unsigned short*)(ws + 112996352);
  unsigned short* VT   = (unsigned short*)(ws + 146550784);
  float* LSUM = (float*)(ws + 163328000);
  float* COH  = (float*)(ws + 163393536);
  if (ws_size < 163393600) return;

  prologue_kernel<<<38848, 256, 0, stream>>>(
      query, key, value, XQ, XK, XV, Wqr, Wqi, Wkr, Wki, Wv, WTQ, WTK, WTV,
      bqr, bqi, bkr, bki, bv, BQ, BK, BV, LSUM, COH);

  proj_fused_kernel<<<dim3(20, 128), 256, 0, stream>>>(
      XQ, XK, XV, WTQ, WTK, WTV, BQ, BK, BV, QCAT, KCAT, VT);

  score_kernel<<<2048, 256, 0, stream>>>(QCAT, KCAT, Pbuf, LSUM, COH);
  pv_kernel<<<512, 256, 0, stream>>>(Pbuf, VT, LSUM, out);
  finalize_kernel<<<1, 1, 0, stream>>>(COH, cw, out + 8388608);
}